// Round 1
// 257.367 us; speedup vs baseline: 1.1764x; 1.1764x over previous
//
#include <hip/hip_runtime.h>
#include <stdint.h>

// CrossNetwork: x:[16384,512] f32, W:[4,512,512] f32 (torch Linear), b:[4,512] f32
// out:[16384, 4*512] f32 = concat of layer outputs.
//
// Algebra: the scalar-residual loop collapses to x_eff = x_i + c_i*1 with
//   c = 0; for j<i: c += dot(x_i,x_j) + c*sum(x_j)
// and (x_i + c*1) @ W^T = x_i @ W^T + c * rowsum(W). So: 4 bf16 MFMA GEMMs +
// per-row scalar stats + rank-1 epilogue.
//
// R3 structure:
//  - dots/sums fused into GEMM epilogue as per-(wave,block-col) PARTIALS
//    (8 disjoint slots per row -> no atomics, no zero-init). The next GEMM
//    folds partials into c[row] with a 128-thread LDS pass.
//  - GEMM main loop: double-buffered LDS, ONE barrier per K-step; the
//    end-of-step __syncthreads vmcnt-drain is the wait for the NEXT tile,
//    so global_load_lds latency hides under current-step MFMAs.
//  - convw+conv0 merged into one prep kernel. 5 dispatches total (was 10).

#define BROWS 16384
#define DIM 512
#define NL 4
#define OUTSTRIDE (NL * DIM)

#define BM 128
#define BN 128
#define BK 32
#define NT (DIM / BK)   // 16 K-steps

typedef unsigned short ushort_t;
typedef __attribute__((ext_vector_type(8))) short bf16x8;
typedef __attribute__((ext_vector_type(4))) float f32x4;

__device__ inline ushort_t f32_to_bf16(float f) {
    union { float f; uint32_t u; } v; v.f = f;
    uint32_t u = v.u;
    uint32_t r = (u + 0x7fffu + ((u >> 16) & 1u)) >> 16;   // RNE
    return (ushort_t)r;
}

__device__ inline float bf16_bits_to_f32(ushort_t u) {
    union { uint32_t u; float f; } v; v.u = ((uint32_t)u) << 16; return v.f;
}

__device__ inline float wave_reduce_sum(float v) {
    #pragma unroll
    for (int off = 32; off > 0; off >>= 1) v += __shfl_down(v, off, 64);
    return v;
}

// ---------------------------------------------------------------------------
// prep: blocks [0,2048): W f32 -> bf16 + wsum[l][e]=sum_d W[l][e][d]
//       blocks [2048,6144): x0 f32 -> bf16 xb0 + sum0[b] (one wave per row)
// ---------------------------------------------------------------------------
__global__ __launch_bounds__(256) void prep_kernel(
    const float* __restrict__ W, const float* __restrict__ x0,
    ushort_t* __restrict__ Wb, float* __restrict__ wsum,
    ushort_t* __restrict__ xb0, float* __restrict__ sum0)
{
    int t = threadIdx.x;
    int wave = t >> 6, lane = t & 63;
    if (blockIdx.x < NL * DIM) {
        int row = blockIdx.x;      // l*512 + e
        const float* wp = W + (size_t)row * DIM;
        float f0 = wp[2 * t], f1 = wp[2 * t + 1];
        ushort_t* wbp = Wb + (size_t)row * DIM;
        wbp[2 * t]     = f32_to_bf16(f0);
        wbp[2 * t + 1] = f32_to_bf16(f1);
        __shared__ float red[4];
        float r = wave_reduce_sum(f0 + f1);
        if (lane == 0) red[wave] = r;
        __syncthreads();
        if (t == 0) wsum[row] = red[0] + red[1] + red[2] + red[3];
    } else {
        int b = (blockIdx.x - NL * DIM) * 4 + wave;
        const float* xp = x0 + (size_t)b * DIM + lane * 8;
        float4 a = ((const float4*)xp)[0];
        float4 c4 = ((const float4*)xp)[1];
        float f[8] = {a.x, a.y, a.z, a.w, c4.x, c4.y, c4.z, c4.w};
        bf16x8 o;
        float s = 0.f;
        #pragma unroll
        for (int i = 0; i < 8; ++i) {
            o[i] = (short)f32_to_bf16(f[i]);
            s += f[i];
        }
        *(bf16x8*)(xb0 + (size_t)b * DIM + lane * 8) = o;
        s = wave_reduce_sum(s);
        if (lane == 0) sum0[b] = s;
    }
}

// ---------------------------------------------------------------------------
// GEMM layer L: y[b][e] = sum_d xL[b][d]*Wb[e][d] + c[b]*wsum[e] + bias[e]
//  - c[b] folded from sum0/psum/pdot partials written by the previous layer.
//  - epilogue writes f32 out, bf16 xb_next, and the NEXT layer's partials:
//      psum[L][pq][b]      += partial rowsum of v            (pq = wn*4+bx)
//      pdot[base+j][pq][b] += partial dot(v, xb_j), j<=L     (base=(L+1)L/2)
//  - K-loop: 2-phase dbuf, one barrier per K-step (T3-minimum).
// grid: 512 blocks 1D (XCD-chunk swizzled), 256 threads.
// ---------------------------------------------------------------------------
template <int L, bool HASNEXT>
__global__ __launch_bounds__(256) void gemm_kernel(
    const ushort_t* __restrict__ xb,     // [4][BROWS][DIM] bf16 bits (base)
    const ushort_t* __restrict__ Wb,     // [512][512] bf16 bits, [e][d], layer L
    const float* __restrict__ bias,      // [512] layer L
    const float* __restrict__ wsum,      // [512] layer L
    float* __restrict__ out,             // stride OUTSTRIDE, column-offset L*512
    ushort_t* __restrict__ xb_next,      // [BROWS][DIM] bf16 or nullptr
    const float* __restrict__ sum0,      // [BROWS]
    float* __restrict__ psum,            // [3][8][BROWS]
    float* __restrict__ pdot)            // [6][8][BROWS]
{
    __shared__ __align__(16) ushort_t sA[2][BM * BK];
    __shared__ __align__(16) ushort_t sB[2][BN * BK];
    __shared__ float sC[BM];

    int tid  = threadIdx.x;
    int wave = tid >> 6;
    int lane = tid & 63;
    int wm = wave >> 1, wn = wave & 1;   // 2x2 wave grid

    // XCD-chunk swizzle: 512 blocks, 8 XCDs round-robin by linear id ->
    // give each XCD a contiguous y-chunk so the 4 x-blocks sharing an
    // A-panel land in one L2.
    int lid  = blockIdx.x;
    int xcd  = lid & 7, slot = lid >> 3;
    int orig = xcd * 64 + slot;          // 512/8 = 64 blocks per XCD
    int bx = orig & 3, by = orig >> 2;
    int bm = by * BM;
    int bn = bx * BN;

    const ushort_t* A = xb + (size_t)L * BROWS * DIM;

    f32x4 acc[4][4] = {};

    int srow = lane >> 2;            // 0..15: row within 16-row staging chunk
    int scol = (lane & 3) * 8;       // 0,8,16,24: elem col
    const ushort_t* gA0 = A  + (size_t)(bm + srow) * DIM + scol;
    const ushort_t* gB0 = Wb + (size_t)(bn + srow) * DIM + scol;

    auto stage = [&](int buf, int k0) {
        #pragma unroll
        for (int t2 = 0; t2 < 2; ++t2) {
            int r = wave * 32 + t2 * 16;                     // wave-uniform
            __builtin_amdgcn_global_load_lds(
                (const __attribute__((address_space(1))) void*)(gA0 + (size_t)r * DIM + k0),
                (__attribute__((address_space(3))) void*)(&sA[buf][r * BK]), 16, 0, 0);
            __builtin_amdgcn_global_load_lds(
                (const __attribute__((address_space(1))) void*)(gB0 + (size_t)r * DIM + k0),
                (__attribute__((address_space(3))) void*)(&sB[buf][r * BK]), 16, 0, 0);
        }
    };

    stage(0, 0);
    __syncthreads();   // drain vmcnt(0): buf0 ready

    int q8 = (lane >> 4) * 8;
    int rr = lane & 15;
    for (int t = 0; t < NT; ++t) {
        int cur = t & 1;
        if (t + 1 < NT) stage(cur ^ 1, (t + 1) * BK);   // in flight across MFMAs
        bf16x8 af[4], bfr[4];
        #pragma unroll
        for (int mi = 0; mi < 4; ++mi)
            af[mi] = *(const bf16x8*)(&sA[cur][(wm * 64 + mi * 16 + rr) * BK + q8]);
        #pragma unroll
        for (int ni = 0; ni < 4; ++ni)
            bfr[ni] = *(const bf16x8*)(&sB[cur][(wn * 64 + ni * 16 + rr) * BK + q8]);
        #pragma unroll
        for (int mi = 0; mi < 4; ++mi)
            #pragma unroll
            for (int ni = 0; ni < 4; ++ni)
                acc[mi][ni] = __builtin_amdgcn_mfma_f32_16x16x32_bf16(
                    af[mi], bfr[ni], acc[mi][ni], 0, 0, 0);
        // single barrier: drains vmcnt(0) (next buffer staged) and lgkmcnt
        // (this buffer's ds_reads retired) => safe to overwrite cur next iter
        __syncthreads();
    }

    // ---- c[row] for this layer from previous layer's partials ----
    if (L > 0) {
        if (tid < BM) {
            int row = bm + tid;
            float c = 0.f;
            #pragma unroll
            for (int j = 0; j < L; ++j) {
                constexpr int pb = L * (L - 1) / 2;
                const float* pd = pdot + ((size_t)(pb + j) * 8) * BROWS + row;
                float d = 0.f;
                #pragma unroll
                for (int p = 0; p < 8; ++p) d += pd[(size_t)p * BROWS];
                float sj;
                if (j == 0) sj = sum0[row];
                else {
                    const float* ps = psum + ((size_t)(j - 1) * 8) * BROWS + row;
                    sj = 0.f;
                    #pragma unroll
                    for (int p = 0; p < 8; ++p) sj += ps[(size_t)p * BROWS];
                }
                c = c + d + c * sj;
            }
            sC[tid] = c;
        }
        __syncthreads();
    }

    // ---- epilogue: out f32, xb_next bf16, next layer's partial stats ----
    // C/D layout (verified m89/m91): col = lane&15, row = (lane>>4)*4 + reg
    int q = lane >> 4, nlane = lane & 15;
    int pq = wn * 4 + bx;                 // partial slot 0..7
    float ws4[4], bs4[4];
    #pragma unroll
    for (int ni = 0; ni < 4; ++ni) {
        int n_g = bn + wn * 64 + ni * 16 + nlane;
        ws4[ni] = wsum[n_g];
        bs4[ni] = bias[n_g];
    }
    #pragma unroll
    for (int mi = 0; mi < 4; ++mi) {
        #pragma unroll
        for (int r = 0; r < 4; ++r) {
            int mloc = wm * 64 + mi * 16 + q * 4 + r;
            int m_g = bm + mloc;
            float c = (L > 0) ? sC[mloc] : 0.f;
            float vsum = 0.f, vdot0 = 0.f, vdot1 = 0.f, vdot2 = 0.f;
            #pragma unroll
            for (int ni = 0; ni < 4; ++ni) {
                int n_g = bn + wn * 64 + ni * 16 + nlane;
                float v = acc[mi][ni][r] + c * ws4[ni] + bs4[ni];
                out[(size_t)m_g * OUTSTRIDE + n_g] = v;
                if constexpr (HASNEXT) {
                    xb_next[(size_t)m_g * DIM + n_g] = f32_to_bf16(v);
                    vsum += v;
                    vdot0 += v * bf16_bits_to_f32(xb[((size_t)0 * BROWS + m_g) * DIM + n_g]);
                    if (L >= 1)
                        vdot1 += v * bf16_bits_to_f32(xb[((size_t)1 * BROWS + m_g) * DIM + n_g]);
                    if (L >= 2)
                        vdot2 += v * bf16_bits_to_f32(xb[((size_t)2 * BROWS + m_g) * DIM + n_g]);
                }
            }
            if constexpr (HASNEXT) {
                #pragma unroll
                for (int off = 8; off > 0; off >>= 1) {   // reduce within 16-lane group
                    vsum  += __shfl_xor(vsum,  off, 64);
                    vdot0 += __shfl_xor(vdot0, off, 64);
                    if (L >= 1) vdot1 += __shfl_xor(vdot1, off, 64);
                    if (L >= 2) vdot2 += __shfl_xor(vdot2, off, 64);
                }
                if (nlane == 0) {
                    constexpr int pbn = (L + 1) * L / 2;   // pair base for layer L+1
                    psum[((size_t)L * 8 + pq) * BROWS + m_g] = vsum;
                    pdot[((size_t)(pbn + 0) * 8 + pq) * BROWS + m_g] = vdot0;
                    if (L >= 1) pdot[((size_t)(pbn + 1) * 8 + pq) * BROWS + m_g] = vdot1;
                    if (L >= 2) pdot[((size_t)(pbn + 2) * 8 + pq) * BROWS + m_g] = vdot2;
                }
            }
        }
    }
}

// ---------------------------------------------------------------------------
extern "C" void kernel_launch(void* const* d_in, const int* in_sizes, int n_in,
                              void* d_out, int out_size, void* d_ws, size_t ws_size,
                              hipStream_t stream) {
    (void)in_sizes; (void)n_in; (void)out_size; (void)ws_size;
    const float* x0   = (const float*)d_in[0];
    const float* W    = (const float*)d_in[1];
    const float* bias = (const float*)d_in[2];
    float* out = (float*)d_out;

    char* ws = (char*)d_ws;
    // workspace layout (bytes):
    //   xb   : 4 * 16384*512 * 2 = 67,108,864
    //   Wb   : 4 * 512*512  * 2 =  2,097,152   @ 67,108,864
    //   wsum : 4 * 512 * 4      =      8,192   @ 69,206,016
    //   sum0 : 16384 * 4        =     65,536   @ 69,214,208
    //   psum : 3*8*16384*4      =  1,572,864   @ 69,279,744
    //   pdot : 6*8*16384*4      =  3,145,728   @ 70,852,608   (~74 MB total)
    ushort_t* xb   = (ushort_t*)ws;
    ushort_t* Wb   = (ushort_t*)(ws + 67108864);
    float*    wsum = (float*)   (ws + 69206016);
    float*    sum0 = (float*)   (ws + 69214208);
    float*    psum = (float*)   (ws + 69279744);
    float*    pdot = (float*)   (ws + 70852608);

    prep_kernel<<<NL * DIM + BROWS / 4, 256, 0, stream>>>(W, x0, Wb, wsum, xb, sum0);

    const int nblk = (BROWS / BM) * (DIM / BN);   // 512
    gemm_kernel<0, true><<<nblk, 256, 0, stream>>>(
        xb, Wb, bias, wsum, out,
        xb + (size_t)1 * BROWS * DIM, sum0, psum, pdot);
    gemm_kernel<1, true><<<nblk, 256, 0, stream>>>(
        xb, Wb + (size_t)1 * DIM * DIM, bias + DIM, wsum + DIM, out + DIM,
        xb + (size_t)2 * BROWS * DIM, sum0, psum, pdot);
    gemm_kernel<2, true><<<nblk, 256, 0, stream>>>(
        xb, Wb + (size_t)2 * DIM * DIM, bias + 2 * DIM, wsum + 2 * DIM, out + 2 * DIM,
        xb + (size_t)3 * BROWS * DIM, sum0, psum, pdot);
    gemm_kernel<3, false><<<nblk, 256, 0, stream>>>(
        xb, Wb + (size_t)3 * DIM * DIM, bias + 3 * DIM, wsum + 3 * DIM, out + 3 * DIM,
        nullptr, sum0, psum, pdot);
}

// Round 2
// 251.487 us; speedup vs baseline: 1.2039x; 1.0234x over previous
//
#include <hip/hip_runtime.h>
#include <stdint.h>

// CrossNetwork: x:[16384,512] f32, W:[4,512,512] f32 (torch Linear), b:[4,512] f32
// out:[16384, 4*512] f32 = concat of layer outputs.
//
// Algebra: the scalar-residual loop collapses to x_eff = x_i + c_i*1 with
//   c = 0; for j<i: c += dot(x_i,x_j) + c*sum(x_j)
// and (x_i + c*1) @ W^T = x_i @ W^T + c * rowsum(W). So: 4 bf16 MFMA GEMMs +
// per-row scalar stats + rank-1 epilogue.
//
// R4 structure (changes vs R3):
//  - Tile 64x128 -> grid 1024 = 4 blocks/CU (was 2): 2x TLP for stall overlap.
//  - K-loop: 3-buffer LDS, stage depth 2, counted s_waitcnt vmcnt(3) + raw
//    s_barrier (T3/T4 minimum port; never vmcnt(0) in steady state) so each
//    stage's HBM latency spans two compute phases.
//  - dots/sums stay fused in the epilogue as 8 per-(block-col,wave-col)
//    partial slots; next GEMM folds them into c[row].

#define BROWS 16384
#define DIM 512
#define NL 4
#define OUTSTRIDE (NL * DIM)

#define BM 64
#define BN 128
#define BK 32
#define NT (DIM / BK)   // 16 K-steps
#define NBUF 3

typedef unsigned short ushort_t;
typedef __attribute__((ext_vector_type(8))) short bf16x8;
typedef __attribute__((ext_vector_type(4))) float f32x4;

__device__ inline ushort_t f32_to_bf16(float f) {
    union { float f; uint32_t u; } v; v.f = f;
    uint32_t u = v.u;
    uint32_t r = (u + 0x7fffu + ((u >> 16) & 1u)) >> 16;   // RNE
    return (ushort_t)r;
}

__device__ inline float bf16_bits_to_f32(ushort_t u) {
    union { uint32_t u; float f; } v; v.u = ((uint32_t)u) << 16; return v.f;
}

__device__ inline float wave_reduce_sum(float v) {
    #pragma unroll
    for (int off = 32; off > 0; off >>= 1) v += __shfl_down(v, off, 64);
    return v;
}

// ---------------------------------------------------------------------------
// prep: blocks [0,2048): W f32 -> bf16 + wsum[l][e]=sum_d W[l][e][d]
//       blocks [2048,6144): x0 f32 -> bf16 xb0 + sum0[b] (one wave per row)
// ---------------------------------------------------------------------------
__global__ __launch_bounds__(256) void prep_kernel(
    const float* __restrict__ W, const float* __restrict__ x0,
    ushort_t* __restrict__ Wb, float* __restrict__ wsum,
    ushort_t* __restrict__ xb0, float* __restrict__ sum0)
{
    int t = threadIdx.x;
    int wave = t >> 6, lane = t & 63;
    if (blockIdx.x < NL * DIM) {
        int row = blockIdx.x;      // l*512 + e
        const float* wp = W + (size_t)row * DIM;
        float f0 = wp[2 * t], f1 = wp[2 * t + 1];
        ushort_t* wbp = Wb + (size_t)row * DIM;
        wbp[2 * t]     = f32_to_bf16(f0);
        wbp[2 * t + 1] = f32_to_bf16(f1);
        __shared__ float red[4];
        float r = wave_reduce_sum(f0 + f1);
        if (lane == 0) red[wave] = r;
        __syncthreads();
        if (t == 0) wsum[row] = red[0] + red[1] + red[2] + red[3];
    } else {
        int b = (blockIdx.x - NL * DIM) * 4 + wave;
        const float* xp = x0 + (size_t)b * DIM + lane * 8;
        float4 a = ((const float4*)xp)[0];
        float4 c4 = ((const float4*)xp)[1];
        float f[8] = {a.x, a.y, a.z, a.w, c4.x, c4.y, c4.z, c4.w};
        bf16x8 o;
        float s = 0.f;
        #pragma unroll
        for (int i = 0; i < 8; ++i) {
            o[i] = (short)f32_to_bf16(f[i]);
            s += f[i];
        }
        *(bf16x8*)(xb0 + (size_t)b * DIM + lane * 8) = o;
        s = wave_reduce_sum(s);
        if (lane == 0) sum0[b] = s;
    }
}

// ---------------------------------------------------------------------------
// GEMM layer L: y[b][e] = sum_d xL[b][d]*Wb[e][d] + c[b]*wsum[e] + bias[e]
//  - 64x128 tile, 4 waves (2m x 2n), per-wave 2x4 frags of 16x16x32.
//  - K-loop: 3-buffer, depth-2 prefetch, counted vmcnt + raw s_barrier.
//    Per-wave stage = 3 global_load_lds (1 A-chunk + 2 B-chunks) => steady
//    state wait is vmcnt(3): current tile ready, next tile still in flight.
//  - epilogue: out f32, bf16 xb_next, next layer's partial stats
//    (8 disjoint slots per row -> no atomics; pq = bx*2 + wn).
// grid: 1024 blocks 1D (XCD-chunk swizzled), 256 threads.
// ---------------------------------------------------------------------------
template <int L, bool HASNEXT>
__global__ __launch_bounds__(256) void gemm_kernel(
    const ushort_t* __restrict__ xb,     // [4][BROWS][DIM] bf16 bits (base)
    const ushort_t* __restrict__ Wb,     // [512][512] bf16 bits, [e][d], layer L
    const float* __restrict__ bias,      // [512] layer L
    const float* __restrict__ wsum,      // [512] layer L
    float* __restrict__ out,             // stride OUTSTRIDE, column-offset L*512
    ushort_t* __restrict__ xb_next,      // [BROWS][DIM] bf16 or nullptr
    const float* __restrict__ sum0,      // [BROWS]
    float* __restrict__ psum,            // [3][8][BROWS]
    float* __restrict__ pdot)            // [6][8][BROWS]
{
    __shared__ __align__(16) ushort_t sA[NBUF][BM * BK];   // 3 x 4 KB
    __shared__ __align__(16) ushort_t sB[NBUF][BN * BK];   // 3 x 8 KB
    __shared__ float sC[BM];

    int tid  = threadIdx.x;
    int wave = tid >> 6;
    int lane = tid & 63;
    int wm = wave >> 1, wn = wave & 1;   // 2x2 wave grid

    // XCD-chunk swizzle: 1024 blocks over 8 XCDs round-robin by linear id ->
    // each XCD gets 32 consecutive row-panels (A working set 2 MB + B 0.5 MB
    // per XCD L2).
    int lid  = blockIdx.x;
    int xcd  = lid & 7, slot = lid >> 3;
    int orig = xcd * 128 + slot;         // 1024/8 = 128 blocks per XCD
    int bx = orig & 3, by = orig >> 2;   // bx in [0,4), by in [0,256)
    int bm = by * BM;
    int bn = bx * BN;

    const ushort_t* A = xb + (size_t)L * BROWS * DIM;

    f32x4 acc[2][4] = {};

    int srow = lane >> 2;            // 0..15: row within 16-row staging chunk
    int scol = (lane & 3) * 8;       // 0,8,16,24: elem col
    const ushort_t* gA0 = A  + (size_t)(bm + srow) * DIM + scol;
    const ushort_t* gB0 = Wb + (size_t)(bn + srow) * DIM + scol;

    auto stage = [&](int buf, int k0) {
        // A: 64 rows -> 1 chunk/wave; B: 128 rows -> 2 chunks/wave.
        // 3 global_load_lds per wave per stage (vmcnt counting relies on this).
        int ra = wave * 16;
        __builtin_amdgcn_global_load_lds(
            (const __attribute__((address_space(1))) void*)(gA0 + (size_t)ra * DIM + k0),
            (__attribute__((address_space(3))) void*)(&sA[buf][ra * BK]), 16, 0, 0);
        #pragma unroll
        for (int t2 = 0; t2 < 2; ++t2) {
            int rb = wave * 32 + t2 * 16;
            __builtin_amdgcn_global_load_lds(
                (const __attribute__((address_space(1))) void*)(gB0 + (size_t)rb * DIM + k0),
                (__attribute__((address_space(3))) void*)(&sB[buf][rb * BK]), 16, 0, 0);
        }
    };

    stage(0, 0);
    stage(1, BK);

    int q8 = (lane >> 4) * 8;
    int rr = lane & 15;
    for (int t = 0; t < NT; ++t) {
        int cur = t % 3;
        // current tile ready; next tile's 3 loads stay in flight (T4)
        if (t < NT - 1) {
            asm volatile("s_waitcnt vmcnt(3)" ::: "memory");
        } else {
            asm volatile("s_waitcnt vmcnt(0)" ::: "memory");
        }
        __builtin_amdgcn_s_barrier();
        __builtin_amdgcn_sched_barrier(0);
        // prefetch t+2 into the buffer step t-1 finished reading
        if (t + 2 < NT) stage((t + 2) % 3, (t + 2) * BK);

        bf16x8 af[2], bfr[4];
        #pragma unroll
        for (int mi = 0; mi < 2; ++mi)
            af[mi] = *(const bf16x8*)(&sA[cur][(wm * 32 + mi * 16 + rr) * BK + q8]);
        #pragma unroll
        for (int ni = 0; ni < 4; ++ni)
            bfr[ni] = *(const bf16x8*)(&sB[cur][(wn * 64 + ni * 16 + rr) * BK + q8]);
        #pragma unroll
        for (int mi = 0; mi < 2; ++mi)
            #pragma unroll
            for (int ni = 0; ni < 4; ++ni)
                acc[mi][ni] = __builtin_amdgcn_mfma_f32_16x16x32_bf16(
                    af[mi], bfr[ni], acc[mi][ni], 0, 0, 0);
    }

    // ---- c[row] for this layer from previous layer's partials ----
    if (L > 0) {
        if (tid < BM) {
            int row = bm + tid;
            float c = 0.f;
            #pragma unroll
            for (int j = 0; j < L; ++j) {
                constexpr int pb = L * (L - 1) / 2;
                const float* pd = pdot + ((size_t)(pb + j) * 8) * BROWS + row;
                float d = 0.f;
                #pragma unroll
                for (int p = 0; p < 8; ++p) d += pd[(size_t)p * BROWS];
                float sj;
                if (j == 0) sj = sum0[row];
                else {
                    const float* ps = psum + ((size_t)(j - 1) * 8) * BROWS + row;
                    sj = 0.f;
                    #pragma unroll
                    for (int p = 0; p < 8; ++p) sj += ps[(size_t)p * BROWS];
                }
                c = c + d + c * sj;
            }
            sC[tid] = c;
        }
        __syncthreads();
    }

    // ---- epilogue: out f32, xb_next bf16, next layer's partial stats ----
    // C/D layout (verified m89/m91): col = lane&15, row = (lane>>4)*4 + reg
    int q = lane >> 4, nlane = lane & 15;
    int pq = bx * 2 + wn;                 // partial slot 0..7
    float ws4[4], bs4[4];
    #pragma unroll
    for (int ni = 0; ni < 4; ++ni) {
        int n_g = bn + wn * 64 + ni * 16 + nlane;
        ws4[ni] = wsum[n_g];
        bs4[ni] = bias[n_g];
    }
    #pragma unroll
    for (int mi = 0; mi < 2; ++mi) {
        #pragma unroll
        for (int r = 0; r < 4; ++r) {
            int mloc = wm * 32 + mi * 16 + q * 4 + r;
            int m_g = bm + mloc;
            float c = (L > 0) ? sC[mloc] : 0.f;
            float vsum = 0.f, vdot0 = 0.f, vdot1 = 0.f, vdot2 = 0.f;
            #pragma unroll
            for (int ni = 0; ni < 4; ++ni) {
                int n_g = bn + wn * 64 + ni * 16 + nlane;
                float v = acc[mi][ni][r] + c * ws4[ni] + bs4[ni];
                out[(size_t)m_g * OUTSTRIDE + n_g] = v;
                if constexpr (HASNEXT) {
                    xb_next[(size_t)m_g * DIM + n_g] = f32_to_bf16(v);
                    vsum += v;
                    vdot0 += v * bf16_bits_to_f32(xb[((size_t)0 * BROWS + m_g) * DIM + n_g]);
                    if (L >= 1)
                        vdot1 += v * bf16_bits_to_f32(xb[((size_t)1 * BROWS + m_g) * DIM + n_g]);
                    if (L >= 2)
                        vdot2 += v * bf16_bits_to_f32(xb[((size_t)2 * BROWS + m_g) * DIM + n_g]);
                }
            }
            if constexpr (HASNEXT) {
                #pragma unroll
                for (int off = 8; off > 0; off >>= 1) {   // reduce within 16-lane group
                    vsum  += __shfl_xor(vsum,  off, 64);
                    vdot0 += __shfl_xor(vdot0, off, 64);
                    if (L >= 1) vdot1 += __shfl_xor(vdot1, off, 64);
                    if (L >= 2) vdot2 += __shfl_xor(vdot2, off, 64);
                }
                if (nlane == 0) {
                    constexpr int pbn = (L + 1) * L / 2;   // pair base for layer L+1
                    psum[((size_t)L * 8 + pq) * BROWS + m_g] = vsum;
                    pdot[((size_t)(pbn + 0) * 8 + pq) * BROWS + m_g] = vdot0;
                    if (L >= 1) pdot[((size_t)(pbn + 1) * 8 + pq) * BROWS + m_g] = vdot1;
                    if (L >= 2) pdot[((size_t)(pbn + 2) * 8 + pq) * BROWS + m_g] = vdot2;
                }
            }
        }
    }
}

// ---------------------------------------------------------------------------
extern "C" void kernel_launch(void* const* d_in, const int* in_sizes, int n_in,
                              void* d_out, int out_size, void* d_ws, size_t ws_size,
                              hipStream_t stream) {
    (void)in_sizes; (void)n_in; (void)out_size; (void)ws_size;
    const float* x0   = (const float*)d_in[0];
    const float* W    = (const float*)d_in[1];
    const float* bias = (const float*)d_in[2];
    float* out = (float*)d_out;

    char* ws = (char*)d_ws;
    // workspace layout (bytes):
    //   xb   : 4 * 16384*512 * 2 = 67,108,864
    //   Wb   : 4 * 512*512  * 2 =  2,097,152   @ 67,108,864
    //   wsum : 4 * 512 * 4      =      8,192   @ 69,206,016
    //   sum0 : 16384 * 4        =     65,536   @ 69,214,208
    //   psum : 3*8*16384*4      =  1,572,864   @ 69,279,744
    //   pdot : 6*8*16384*4      =  3,145,728   @ 70,852,608   (~74 MB total)
    ushort_t* xb   = (ushort_t*)ws;
    ushort_t* Wb   = (ushort_t*)(ws + 67108864);
    float*    wsum = (float*)   (ws + 69206016);
    float*    sum0 = (float*)   (ws + 69214208);
    float*    psum = (float*)   (ws + 69279744);
    float*    pdot = (float*)   (ws + 70852608);

    prep_kernel<<<NL * DIM + BROWS / 4, 256, 0, stream>>>(W, x0, Wb, wsum, xb, sum0);

    const int nblk = (BROWS / BM) * (DIM / BN);   // 1024
    gemm_kernel<0, true><<<nblk, 256, 0, stream>>>(
        xb, Wb, bias, wsum, out,
        xb + (size_t)1 * BROWS * DIM, sum0, psum, pdot);
    gemm_kernel<1, true><<<nblk, 256, 0, stream>>>(
        xb, Wb + (size_t)1 * DIM * DIM, bias + DIM, wsum + DIM, out + DIM,
        xb + (size_t)2 * BROWS * DIM, sum0, psum, pdot);
    gemm_kernel<2, true><<<nblk, 256, 0, stream>>>(
        xb, Wb + (size_t)2 * DIM * DIM, bias + 2 * DIM, wsum + 2 * DIM, out + 2 * DIM,
        xb + (size_t)3 * BROWS * DIM, sum0, psum, pdot);
    gemm_kernel<3, false><<<nblk, 256, 0, stream>>>(
        xb, Wb + (size_t)3 * DIM * DIM, bias + 3 * DIM, wsum + 3 * DIM, out + 3 * DIM,
        nullptr, sum0, psum, pdot);
}